// Round 6
// baseline (5545.072 us; speedup 1.0000x reference)
//
#include <hip/hip_runtime.h>
#include <cmath>

typedef __bf16 bf16;
typedef float f32x4 __attribute__((ext_vector_type(4)));
typedef bf16 bf16x8 __attribute__((ext_vector_type(8)));
typedef bf16 bf16x4 __attribute__((ext_vector_type(4)));

#define DEVINL __device__ __forceinline__

DEVINL void gload_lds16(const void* g, void* l) {
  __builtin_amdgcn_global_load_lds(
      (const __attribute__((address_space(1))) void*)g,
      (__attribute__((address_space(3))) void*)l, 16, 0, 0);
}

DEVINL float sigf(float x) { return 1.f / (1.f + __expf(-x)); }

// Watchdog: normal waits <10us; 1<<20 sleep(2) spins ~0.1s — converts any
// sync bug into a wrong-answer report instead of a GPU hang.
DEVINL void waitflag(unsigned* f, unsigned tgt) {
  int spins = 0;
  while (__hip_atomic_load(f, __ATOMIC_RELAXED, __HIP_MEMORY_SCOPE_AGENT) < tgt) {
    __builtin_amdgcn_s_sleep(2);
    if (++spins > (1 << 20)) break;
  }
}

#define MFMA __builtin_amdgcn_mfma_f32_16x16x32_bf16

// ---------------- prep: plain weight casts + x prep + flag zero ----------------
__global__ void prep_all_k(
    const float* __restrict__ x,
    const float* __restrict__ eWih0, const float* __restrict__ eWhh0,
    const float* __restrict__ eWih1, const float* __restrict__ eWhh1,
    const float* __restrict__ dWih0, const float* __restrict__ dWhh0,
    const float* __restrict__ dWih1, const float* __restrict__ dWhh1,
    const float* __restrict__ fcW,
    bf16* __restrict__ Wih_e0, bf16* __restrict__ Whh_e0,
    bf16* __restrict__ Wih_e1, bf16* __restrict__ Whh_e1,
    bf16* __restrict__ Wih_d0, bf16* __restrict__ Whh_d0,
    bf16* __restrict__ Wih_d1, bf16* __restrict__ Whh_d1,
    bf16* __restrict__ Wfc, bf16* __restrict__ xe, bf16* __restrict__ xd,
    unsigned* __restrict__ bars) {
  if (blockIdx.x < 128) bars[blockIdx.x * 256 + threadIdx.x] = 0;
  int i = blockIdx.x * 256 + threadIdx.x;
  if (i < 2097152) { Wih_e0[i] = (bf16)eWih0[i]; return; } i -= 2097152;
  if (i < 4194304) { Whh_e0[i] = (bf16)eWhh0[i]; return; } i -= 4194304;
  if (i < 4194304) { Wih_e1[i] = (bf16)eWih1[i]; return; } i -= 4194304;
  if (i < 4194304) { Whh_e1[i] = (bf16)eWhh1[i]; return; } i -= 4194304;
  if (i < 2097152) { Wih_d0[i] = (bf16)dWih0[i]; return; } i -= 2097152;
  if (i < 4194304) { Whh_d0[i] = (bf16)dWhh0[i]; return; } i -= 4194304;
  if (i < 4194304) { Wih_d1[i] = (bf16)dWih1[i]; return; } i -= 4194304;
  if (i < 4194304) { Whh_d1[i] = (bf16)dWhh1[i]; return; } i -= 4194304;
  if (i < 524288) { Wfc[i] = (bf16)fcW[i]; return; } i -= 524288;
  if (i < 4194304) {
    int ii = i & 511;
    int b = (i >> 9) & 63;
    int t = i >> 15;
    xe[i] = (bf16)x[b * 65536 + t * 512 + ii];
    xd[i] = (t == 0) ? (bf16)0.f : (bf16)x[b * 65536 + (t - 1) * 512 + ii];
  }
}

// ---------------- GEMM: C[M,N] = A[M,K] @ W[N,K]^T (proven; pre-GEMM + FC) ----
__global__ __launch_bounds__(256) void gemm_bt_k(
    const bf16* __restrict__ A, const bf16* __restrict__ Bw,
    bf16* __restrict__ Cbf, float* __restrict__ Cf32, const float* __restrict__ bias,
    int M, int N, int K, int mode) {
  __shared__ __attribute__((aligned(16))) bf16 As[128 * 32];
  __shared__ __attribute__((aligned(16))) bf16 Bs[128 * 32];
  const int tid = threadIdx.x;
  const int lane = tid & 63;
  const int wave = tid >> 6;
  const int wm = wave >> 1, wn = wave & 1;
  const int m0 = blockIdx.y * 128;
  const int n0 = blockIdx.x * 128;

  f32x4 acc[4][4];
  for (int i = 0; i < 4; ++i)
    for (int j = 0; j < 4; ++j) acc[i][j] = 0;

  const int r1 = tid >> 2;
  const int kc = (tid & 3) * 8;
  const int fr = lane & 15;
  const int fk = (lane >> 4) * 8;

  for (int k0 = 0; k0 < K; k0 += 32) {
    gload_lds16(A + (size_t)(m0 + r1) * K + k0 + kc, As + tid * 8);
    gload_lds16(A + (size_t)(m0 + 64 + r1) * K + k0 + kc, As + 2048 + tid * 8);
    gload_lds16(Bw + (size_t)(n0 + r1) * K + k0 + kc, Bs + tid * 8);
    gload_lds16(Bw + (size_t)(n0 + 64 + r1) * K + k0 + kc, Bs + 2048 + tid * 8);
    __syncthreads();
    bf16x8 af[4], bw[4];
    for (int i = 0; i < 4; ++i)
      af[i] = *(const bf16x8*)(As + (wm * 64 + i * 16 + fr) * 32 + fk);
    for (int j = 0; j < 4; ++j)
      bw[j] = *(const bf16x8*)(Bs + (wn * 64 + j * 16 + fr) * 32 + fk);
    for (int i = 0; i < 4; ++i)
      for (int j = 0; j < 4; ++j)
        acc[i][j] = MFMA(af[i], bw[j], acc[i][j], 0, 0, 0);
    __syncthreads();
  }

  const int col16 = lane & 15;
  const int rq = (lane >> 4) * 4;
  for (int i = 0; i < 4; ++i)
    for (int j = 0; j < 4; ++j)
      for (int r = 0; r < 4; ++r) {
        int row = m0 + wm * 64 + i * 16 + rq + r;
        int col = n0 + wn * 64 + j * 16 + col16;
        float v = acc[i][j][r];
        if (mode == 0) {
          Cbf[(size_t)row * N + col] = (bf16)v;
        } else {
          v = sigf(v + bias[col]);
          int b = row & 63, t = row >> 6;
          Cf32[(size_t)b * (128 * 512) + (size_t)t * 512 + col] = v;
        }
      }
}

// ---------------- persistent 3-stage pipelined LSTM phase (cooperative) ----------
// Grid 192 blocks, 1 WG/CU. NEW in R11:
//  kind 0 (bid 0..63):   A-cells, 16 h-cols each, recurrent K=1024 + G aux.
//  kind 1 (bid 64..127): GB-GEMM, 64 gate-rows each: GB[t] = h_A[t] @ WihB^T.
//  kind 2 (bid 128..191):B-cells, 16 h-cols each, recurrent K=1024 + GB aux.
//  - every sync pool is 64 blocks (straggler max over 64, was 128).
//  - wave q owns gate q (full K): NO k-quarter reduce; single gt write + 1 bar.
//  - LDS weight stride 1028 elems -> conflict-free ds_read_b128.
//  - GB is an 8-slot window (4 MB): producers wait bF>=t-7 before slot reuse;
//    consumers read GB via AGENT ATOMIC u64 loads (no stale-L2 on slot reuse).
//  - flags: aF (A publishes), gF (GB), bF (B); 8 replicas each; publish after
//    __syncthreads vmcnt-drain of agent-scope data stores (R2-proven pattern).
struct PK {
  const bf16* G;
  const bf16* WA; const float* bA; const bf16* hA0; const float* cA0; bf16* RA;
  const bf16* WG; bf16* GB;
  const bf16* WB; const float* bB; const bf16* hB0; const float* cB0; bf16* RB;
  bf16* HfA; bf16* HfB;
  unsigned* bar;
};

__global__ __launch_bounds__(256, 1) void phase_k(PK P) {
  extern __shared__ __attribute__((aligned(16))) char smem[];
  bf16* WS = (bf16*)smem;                 // 64 rows x 1028 stride (131584 B)
  float* gt = (float*)(smem + 131584);    // [64][68] f32 (17408 B)

  const int tid = threadIdx.x;
  const int lane = tid & 63;
  const int q = tid >> 6;                 // wave = gate (cells) / n-frag (GB)
  const int bid = blockIdx.x;
  const int kind = bid >> 6;              // 0 A-cell, 1 GB-gemm, 2 B-cell
  const int slot = bid & 63;
  const int fr = lane & 15;
  const int fk = (lane >> 4) * 8;
  const int rq = (lane >> 4) * 4;
  const int cb = tid >> 2;                // batch row 0..63
  const int cj = (tid & 3) * 4;           // 4 h-cols per thread
  const int j0 = slot * 16;

  unsigned* aF = P.bar;
  unsigned* gF = P.bar + 4096;
  unsigned* bF = P.bar + 8192;
  const int rep = (bid & 7) << 9;

  // ---- stage 64x1024 bf16 weight tile (all kinds identical footprint) ----
  {
    const int c = tid >> 2, s = tid & 3;
    const bf16* Wsrc = (kind == 0) ? P.WA : (kind == 1) ? P.WG : P.WB;
    const int nr = (kind == 1) ? (slot * 64 + c) : ((c >> 4) * 1024 + j0 + (c & 15));
    const bf16* src = Wsrc + (size_t)nr * 1024 + s * 256;
    bf16* dst = WS + c * 1028 + s * 256;
#pragma unroll
    for (int w = 0; w < 32; ++w)
      *(bf16x8*)(dst + w * 8) = *(const bf16x8*)(src + w * 8);
  }
  float bsr[4][4], creg[4];
  if (kind != 1) {
    const float* bias = (kind == 2) ? P.bB : P.bA;
    const float* c0 = (kind == 2) ? P.cB0 : P.cA0;
#pragma unroll
    for (int g = 0; g < 4; ++g)
#pragma unroll
      for (int r = 0; r < 4; ++r)
        bsr[g][r] = bias[g * 1024 + j0 + cj + r];
#pragma unroll
    for (int r = 0; r < 4; ++r)
      creg[r] = c0 ? c0[cb * 1024 + j0 + cj + r] : 0.f;
  }
  __syncthreads();

  const bf16* wq = WS + (q * 16 + fr) * 1028 + fk;

  for (int t = 0; t < 128; ++t) {
    bf16x4 graw[4];
    // A aux (precomputed G): safe to load before the wait
    if (kind == 0) {
      const bf16* Gt = P.G + (size_t)t * 262144 + (size_t)cb * 4096 + j0 + cj;
#pragma unroll
      for (int g = 0; g < 4; ++g) graw[g] = *(const bf16x4*)(Gt + g * 1024);
    }

    // ---- waits (layer-scoped, 64-wide pools, distributed flags) ----
    if (kind == 0) {
      if (t > 0 && tid < 64) waitflag(aF + rep + tid * 8, (unsigned)t);
    } else if (kind == 1) {
      if (tid < 64) {
        waitflag(aF + rep + tid * 8, (unsigned)(t + 1));
        if (t >= 8) waitflag(bF + rep + tid * 8, (unsigned)(t - 7));  // window free
      }
    } else {
      if (tid < 64) waitflag(gF + rep + tid * 8, (unsigned)(t + 1));
      else if (t > 0 && tid < 128) waitflag(bF + rep + (tid - 64) * 8, (unsigned)t);
    }
    __syncthreads();

    // B aux (GB window slot): MUST be read after the wait; atomic loads bypass
    // stale XCD-L2 copies from the slot's previous use.
    if (kind == 2) {
      const bf16* Gt = P.GB + (size_t)(t & 7) * 262144 + (size_t)cb * 4096 + j0 + cj;
#pragma unroll
      for (int g = 0; g < 4; ++g) {
        union { unsigned long long u; bf16x4 v; } cv;
        cv.u = __hip_atomic_load((const unsigned long long*)(Gt + g * 1024),
                                 __ATOMIC_RELAXED, __HIP_MEMORY_SCOPE_AGENT);
        graw[g] = cv.v;
      }
    }

    const bf16* src = (kind == 0)
        ? ((t == 0) ? P.hA0 : P.RA + (size_t)(t - 1) * 65536)
        : (kind == 1) ? (P.RA + (size_t)t * 65536)
                      : ((t == 0) ? P.hB0 : P.RB + (size_t)(t - 1) * 65536);

    f32x4 acc[4];
#pragma unroll
    for (int i = 0; i < 4; ++i) acc[i] = 0;

    if (src) {
      const bf16* ap = src + fk;
      bf16x8 ab[2][16];
#pragma unroll
      for (int bt = 0; bt < 4; ++bt)
#pragma unroll
        for (int kk = 0; kk < 4; ++kk)
          ab[0][bt * 4 + kk] = *(const bf16x8*)(ap + (bt * 16 + fr) * 1024 + kk * 32);
#pragma unroll
      for (int ch = 0; ch < 8; ++ch) {
        if (ch < 7) {
#pragma unroll
          for (int bt = 0; bt < 4; ++bt)
#pragma unroll
            for (int kk = 0; kk < 4; ++kk)
              ab[(ch + 1) & 1][bt * 4 + kk] =
                  *(const bf16x8*)(ap + (bt * 16 + fr) * 1024 + (ch + 1) * 128 + kk * 32);
        }
#pragma unroll
        for (int kk = 0; kk < 4; ++kk) {
          bf16x8 w = *(const bf16x8*)(wq + (ch * 4 + kk) * 32);
#pragma unroll
          for (int bt = 0; bt < 4; ++bt)
            acc[bt] = MFMA(ab[ch & 1][bt * 4 + kk], w, acc[bt], 0, 0, 0);
        }
      }
    }

    if (kind == 1) {
      // ---- GB epilogue: agent-scope 2B stores into window slot ----
      bf16* GBt = P.GB + (size_t)(t & 7) * 262144;
#pragma unroll
      for (int bt = 0; bt < 4; ++bt)
#pragma unroll
        for (int r = 0; r < 4; ++r) {
          int row = bt * 16 + rq + r;
          union { bf16 h; unsigned short u; } cv;
          cv.h = (bf16)acc[bt][r];
          __hip_atomic_store(
              (unsigned short*)(GBt + (size_t)row * 4096 + slot * 64 + q * 16 + fr),
              cv.u, __ATOMIC_RELAXED, __HIP_MEMORY_SCOPE_AGENT);
        }
      __syncthreads();  // drain vmcnt: GB stores visible before flag
      if (tid < 8)
        __hip_atomic_store(gF + (tid << 9) + slot * 8, (unsigned)(t + 1),
                           __ATOMIC_RELAXED, __HIP_MEMORY_SCOPE_AGENT);
    } else {
      // ---- cell epilogue: single-round gate exchange via LDS ----
#pragma unroll
      for (int bt = 0; bt < 4; ++bt)
#pragma unroll
        for (int r = 0; r < 4; ++r)
          gt[(bt * 16 + rq + r) * 68 + q * 16 + fr] = acc[bt][r];
      __syncthreads();
      float hn[4];
#pragma unroll
      for (int r = 0; r < 4; ++r) {
        int jj = cj + r;
        float gi = gt[cb * 68 + jj]      + (float)graw[0][r] + bsr[0][r];
        float gf = gt[cb * 68 + 16 + jj] + (float)graw[1][r] + bsr[1][r];
        float gg = gt[cb * 68 + 32 + jj] + (float)graw[2][r] + bsr[2][r];
        float go = gt[cb * 68 + 48 + jj] + (float)graw[3][r] + bsr[3][r];
        float cn = sigf(gf) * creg[r] + sigf(gi) * tanhf(gg);
        creg[r] = cn;
        hn[r] = sigf(go) * tanhf(cn);
      }
      bf16* R = (kind == 2) ? P.RB : P.RA;
      union { bf16 h[4]; unsigned long long u; } pk;
#pragma unroll
      for (int r = 0; r < 4; ++r) pk.h[r] = (bf16)hn[r];
      __hip_atomic_store(
          (unsigned long long*)(R + (size_t)t * 65536 + cb * 1024 + j0 + cj),
          pk.u, __ATOMIC_RELAXED, __HIP_MEMORY_SCOPE_AGENT);
      bf16* Hf = (kind == 2) ? P.HfB : P.HfA;
      if (Hf && t == 127) {
        union { bf16 h[4]; unsigned long long u; } e2;
#pragma unroll
        for (int r = 0; r < 4; ++r) e2.h[r] = (bf16)tanhf(hn[r]);
        __hip_atomic_store((unsigned long long*)(Hf + cb * 1024 + j0 + cj),
                           e2.u, __ATOMIC_RELAXED, __HIP_MEMORY_SCOPE_AGENT);
      }
      __syncthreads();  // drain vmcnt: h stores visible before flag
      unsigned* F = (kind == 2) ? bF : aF;
      if (tid < 8)
        __hip_atomic_store(F + (tid << 9) + slot * 8, (unsigned)(t + 1),
                           __ATOMIC_RELAXED, __HIP_MEMORY_SCOPE_AGENT);
    }
  }
}

// ---------------- host orchestration ----------------
extern "C" void kernel_launch(void* const* d_in, const int* in_sizes, int n_in,
                              void* d_out, int out_size, void* d_ws, size_t ws_size,
                              hipStream_t stream) {
  (void)in_sizes; (void)n_in; (void)out_size; (void)ws_size;
  const float* x      = (const float*)d_in[0];
  const float* dec_c0 = (const float*)d_in[1];
  const float* eWih0 = (const float*)d_in[2];
  const float* eWhh0 = (const float*)d_in[3];
  const float* eb0   = (const float*)d_in[4];
  const float* eWih1 = (const float*)d_in[5];
  const float* eWhh1 = (const float*)d_in[6];
  const float* eb1   = (const float*)d_in[7];
  const float* dWih0 = (const float*)d_in[8];
  const float* dWhh0 = (const float*)d_in[9];
  const float* db0   = (const float*)d_in[10];
  const float* dWih1 = (const float*)d_in[11];
  const float* dWhh1 = (const float*)d_in[12];
  const float* db1   = (const float*)d_in[13];
  const float* fcW   = (const float*)d_in[14];
  const float* fcb   = (const float*)d_in[15];
  float* out = (float*)d_out;

  const int H = 1024, I = 512, T = 128, B = 64;
  const int BH = B * H;
  const size_t TBI = (size_t)T * B * I;
  const size_t TBH = (size_t)T * B * H;
  const int SMEM = 148992;  // 64*1028*2 (weights) + 64*68*4 (gt)

  char* p = (char*)d_ws;
  auto alloc = [&](size_t bytes) -> char* {
    char* r = p; p += (bytes + 255) & ~(size_t)255; return r;
  };
  bf16* Wih_e0 = (bf16*)alloc((size_t)4 * H * I * 2);
  bf16* Whh_e0 = (bf16*)alloc((size_t)4 * H * H * 2);
  bf16* Wih_e1 = (bf16*)alloc((size_t)4 * H * H * 2);
  bf16* Whh_e1 = (bf16*)alloc((size_t)4 * H * H * 2);
  bf16* Wih_d0 = (bf16*)alloc((size_t)4 * H * I * 2);
  bf16* Whh_d0 = (bf16*)alloc((size_t)4 * H * H * 2);
  bf16* Wih_d1 = (bf16*)alloc((size_t)4 * H * H * 2);
  bf16* Whh_d1 = (bf16*)alloc((size_t)4 * H * H * 2);
  bf16* Wfc = (bf16*)alloc((size_t)I * H * 2);
  bf16* xe = (bf16*)alloc(TBI * 2);
  bf16* xd = (bf16*)alloc(TBI * 2);
  bf16* henc0 = (bf16*)alloc((size_t)BH * 2);
  bf16* henc1 = (bf16*)alloc((size_t)BH * 2);
  unsigned* bars = (unsigned*)alloc(131072);
  bf16* G   = (bf16*)alloc((size_t)T * B * 4 * H * 2);      // 64 MB, reused e/d
  bf16* GBw = (bf16*)alloc((size_t)8 * B * 4 * H * 2);      // 4 MB window
  bf16* RA  = (bf16*)alloc(TBH * 2);                        // reused e/d
  bf16* RB  = (bf16*)alloc(TBH * 2);                        // reused e/d

  hipFuncSetAttribute((const void*)phase_k,
                      hipFuncAttributeMaxDynamicSharedMemorySize, SMEM);

  prep_all_k<<<133120, 256, 0, stream>>>(x, eWih0, eWhh0, eWih1, eWhh1,
                                         dWih0, dWhh0, dWih1, dWhh1, fcW,
                                         Wih_e0, Whh_e0, Wih_e1, Whh_e1,
                                         Wih_d0, Whh_d0, Wih_d1, Whh_d1,
                                         Wfc, xe, xd, bars);

  auto coop = [&](PK& pk) {
    void* args[] = { (void*)&pk };
    hipLaunchCooperativeKernel((void*)phase_k, dim3(192), dim3(256), args,
                               SMEM, stream);
  };

  // ---- encoder ----
  gemm_bt_k<<<dim3(32, 64), 256, 0, stream>>>(xe, Wih_e0, G, nullptr, nullptr,
                                              8192, 4096, 512, 0);
  PK Pe = { G, Whh_e0, eb0, nullptr, nullptr, RA,
            Wih_e1, GBw,
            Whh_e1, eb1, nullptr, nullptr, RB,
            henc0, henc1, bars };
  coop(Pe);

  // ---- decoder ----
  gemm_bt_k<<<dim3(32, 64), 256, 0, stream>>>(xd, Wih_d0, G, nullptr, nullptr,
                                              8192, 4096, 512, 0);
  PK Pd = { G, Whh_d0, db0, henc0, dec_c0, RA,
            Wih_d1, GBw,
            Whh_d1, db1, henc1, dec_c0 + BH, RB,
            nullptr, nullptr, bars + 16384 };
  coop(Pd);

  // ---- FC: sigmoid(RB @ fcW^T + fcb), permute [t,b]->[b,t] ----
  gemm_bt_k<<<dim3(4, 64), 256, 0, stream>>>(RB, Wfc, nullptr, out, fcb,
                                             8192, 512, 1024, 1);
}

// Round 7
// 2785.366 us; speedup vs baseline: 1.9908x; 1.9908x over previous
//
#include <hip/hip_runtime.h>
#include <cmath>

typedef __bf16 bf16;
typedef float f32x4 __attribute__((ext_vector_type(4)));
typedef bf16 bf16x8 __attribute__((ext_vector_type(8)));
typedef bf16 bf16x2 __attribute__((ext_vector_type(2)));

#define DEVINL __device__ __forceinline__

DEVINL void gload_lds16(const void* g, void* l) {
  __builtin_amdgcn_global_load_lds(
      (const __attribute__((address_space(1))) void*)g,
      (__attribute__((address_space(3))) void*)l, 16, 0, 0);
}

DEVINL float sigf(float x) { return 1.f / (1.f + __expf(-x)); }

// Watchdog: normal waits <10us; 1<<20 sleep(2) spins ~0.1s — converts any
// sync bug into a wrong-answer report instead of a GPU hang.
DEVINL void waitflag(unsigned* f, unsigned tgt) {
  int spins = 0;
  while (__hip_atomic_load(f, __ATOMIC_RELAXED, __HIP_MEMORY_SCOPE_AGENT) < tgt) {
    __builtin_amdgcn_s_sleep(2);
    if (++spins > (1 << 20)) break;
  }
}

#define MFMA __builtin_amdgcn_mfma_f32_16x16x32_bf16

// ---------------- fused prep: weight casts + x prep + flag zero (R2-proven) ----
__global__ void prep_all_k(
    const float* __restrict__ x,
    const float* __restrict__ eWih0, const float* __restrict__ eWhh0,
    const float* __restrict__ eWih1, const float* __restrict__ eWhh1,
    const float* __restrict__ dWih0, const float* __restrict__ dWhh0,
    const float* __restrict__ dWih1, const float* __restrict__ dWhh1,
    const float* __restrict__ fcW,
    bf16* __restrict__ Wih_e0, bf16* __restrict__ Whh_e0, bf16* __restrict__ Wcat_e1,
    bf16* __restrict__ Wih_d0, bf16* __restrict__ Whh_d0, bf16* __restrict__ Wcat_d1,
    bf16* __restrict__ Wfc, bf16* __restrict__ xe, bf16* __restrict__ xd,
    unsigned* __restrict__ bars) {
  if (blockIdx.x < 128) bars[blockIdx.x * 256 + threadIdx.x] = 0;
  int i = blockIdx.x * 256 + threadIdx.x;
  if (i < 2097152) { Wih_e0[i] = (bf16)eWih0[i]; return; }
  i -= 2097152;
  if (i < 4194304) { Whh_e0[i] = (bf16)eWhh0[i]; return; }
  i -= 4194304;
  if (i < 8388608) {
    int k = i & 2047, r = i >> 11;
    Wcat_e1[i] = (bf16)((k < 1024) ? eWih1[r * 1024 + k] : eWhh1[r * 1024 + k - 1024]);
    return;
  }
  i -= 8388608;
  if (i < 2097152) { Wih_d0[i] = (bf16)dWih0[i]; return; }
  i -= 2097152;
  if (i < 4194304) { Whh_d0[i] = (bf16)dWhh0[i]; return; }
  i -= 4194304;
  if (i < 8388608) {
    int k = i & 2047, r = i >> 11;
    Wcat_d1[i] = (bf16)((k < 1024) ? dWih1[r * 1024 + k] : dWhh1[r * 1024 + k - 1024]);
    return;
  }
  i -= 8388608;
  if (i < 524288) { Wfc[i] = (bf16)fcW[i]; return; }
  i -= 524288;
  if (i < 4194304) {
    int ii = i & 511;
    int b = (i >> 9) & 63;
    int t = i >> 15;
    xe[i] = (bf16)x[b * 65536 + t * 512 + ii];
    xd[i] = (t == 0) ? (bf16)0.f : (bf16)x[b * 65536 + (t - 1) * 512 + ii];
  }
}

// ---------------- GEMM: C[M,N] = A[M,K] @ W[N,K]^T (bf16 in, f32 acc) ----------
// mode 0: C bf16 row-major.  mode 1: FC epilogue, A row-major.
// mode 2: FC epilogue, A in jb-layout [t][k/8][b][8] (the h-ring layout).
__global__ __launch_bounds__(256) void gemm_bt_k(
    const bf16* __restrict__ A, const bf16* __restrict__ Bw,
    bf16* __restrict__ Cbf, float* __restrict__ Cf32, const float* __restrict__ bias,
    int M, int N, int K, int mode) {
  __shared__ __attribute__((aligned(16))) bf16 As[128 * 32];
  __shared__ __attribute__((aligned(16))) bf16 Bs[128 * 32];
  const int tid = threadIdx.x;
  const int lane = tid & 63;
  const int wave = tid >> 6;
  const int wm = wave >> 1, wn = wave & 1;
  const int m0 = blockIdx.y * 128;
  const int n0 = blockIdx.x * 128;

  f32x4 acc[4][4];
  for (int i = 0; i < 4; ++i)
    for (int j = 0; j < 4; ++j) acc[i][j] = 0;

  const int r1 = tid >> 2;
  const int kc = (tid & 3) * 8;
  const int fr = lane & 15;
  const int fk = (lane >> 4) * 8;

  for (int k0 = 0; k0 < K; k0 += 32) {
    const bf16 *a0, *a1;
    if (mode == 2) {
      int ra = m0 + r1, rb = m0 + 64 + r1;
      size_t ko = (size_t)((k0 + kc) >> 3) * 512;
      a0 = A + (size_t)(ra >> 6) * 65536 + ko + (ra & 63) * 8;
      a1 = A + (size_t)(rb >> 6) * 65536 + ko + (rb & 63) * 8;
    } else {
      a0 = A + (size_t)(m0 + r1) * K + k0 + kc;
      a1 = A + (size_t)(m0 + 64 + r1) * K + k0 + kc;
    }
    gload_lds16(a0, As + tid * 8);
    gload_lds16(a1, As + 2048 + tid * 8);
    gload_lds16(Bw + (size_t)(n0 + r1) * K + k0 + kc, Bs + tid * 8);
    gload_lds16(Bw + (size_t)(n0 + 64 + r1) * K + k0 + kc, Bs + 2048 + tid * 8);
    __syncthreads();
    bf16x8 af[4], bw[4];
    for (int i = 0; i < 4; ++i)
      af[i] = *(const bf16x8*)(As + (wm * 64 + i * 16 + fr) * 32 + fk);
    for (int j = 0; j < 4; ++j)
      bw[j] = *(const bf16x8*)(Bs + (wn * 64 + j * 16 + fr) * 32 + fk);
    for (int i = 0; i < 4; ++i)
      for (int j = 0; j < 4; ++j)
        acc[i][j] = MFMA(af[i], bw[j], acc[i][j], 0, 0, 0);
    __syncthreads();
  }

  const int col16 = lane & 15;
  const int rq = (lane >> 4) * 4;
  for (int i = 0; i < 4; ++i)
    for (int j = 0; j < 4; ++j)
      for (int r = 0; r < 4; ++r) {
        int row = m0 + wm * 64 + i * 16 + rq + r;
        int col = n0 + wn * 64 + j * 16 + col16;
        float v = acc[i][j][r];
        if (mode == 0) {
          Cbf[(size_t)row * N + col] = (bf16)v;
        } else {
          v = sigf(v + bias[col]);
          int b = row & 63, t = row >> 6;
          Cf32[(size_t)b * (128 * 512) + (size_t)t * 512 + col] = v;
        }
      }
}

// ---------------- persistent two-layer phase kernel (cooperative) ----------------
// R5-proven structure (128 A-blocks + 128 B-blocks, K-quarter waves, distributed
// flags, G prefetch before wait). NEW in R12: h-rings use jb-major layout
//   R[t][jb][b][8cols]  (element = t*65536 + jb*512 + b*8 + c)
// so each block's per-step h store is 1 KB CONTIGUOUS = 8 full 128B lines.
// This kills the partial-line write-allocate RMW (~3 MB/step of HBM FETCH,
// the R5 cadence serializer). Consumer loads: bf16x8 at k8*512 + row*8.
struct PK {
  const bf16* G;
  const bf16* WhhA; const float* bA; const bf16* hA0; const float* cA0; bf16* RA;
  const bf16* WcatB; const float* bB; const bf16* hB0; const float* cB0; bf16* RB;
  bf16* HfA; bf16* HfB;
  unsigned* bar;
};

__global__ __launch_bounds__(256, 1) void phase_k(PK P) {
  extern __shared__ __attribute__((aligned(16))) char smem[];
  bf16* WS = (bf16*)smem;                       // weight tile, padded rows
  float* gt = (float*)(smem + 131584);          // [2][64][33]
#define GT(h, row, col) gt[(h) * 2112 + (row) * 33 + (col)]

  const int tid = threadIdx.x;
  const int lane = tid & 63;
  const int q = tid >> 6;                       // wave = K-quarter 0..3
  const int bid = blockIdx.x;
  const int half = bid >> 7;
  const int jb = bid & 127;                     // block's col-octet (j0 = jb*8)
  const int j0 = jb * 8;
  const int fr = lane & 15;
  const int fk = (lane >> 4) * 8;
  const int kh = lane >> 4;                     // k8 sub-index 0..3
  const int rq = (lane >> 4) * 4;
  const int cb = tid >> 2;                      // cell batch
  const int cj = (tid & 3) * 2;                 // cell col pair

  const int RS = half ? 2056 : 1032;            // LDS weight row stride (elems)
  const int KQ = half ? 512 : 256;              // K quarter width

  unsigned* aF = P.bar;
  unsigned* bF = P.bar + 8192;
  const int rep = (bid & 7) << 10;

  const bf16* wsc0 = WS + fr * RS + q * KQ + fk;          // cols 0..15
  const bf16* wsc1 = WS + (16 + fr) * RS + q * KQ + fk;   // cols 16..31

  // ---- one-time weight staging into LDS ----
  {
    const int c = tid >> 3;                     // gate-col 0..31
    const int s = tid & 7;                      // segment
    const int nr = (c >> 3) * 1024 + j0 + (c & 7);
    if (half == 0) {
      const bf16* src = P.WhhA + (size_t)nr * 1024 + s * 128;
      bf16* dst = WS + c * 1032 + s * 128;
#pragma unroll
      for (int w = 0; w < 16; ++w)
        *(bf16x8*)(dst + w * 8) = *(const bf16x8*)(src + w * 8);
    } else {
      const bf16* src = P.WcatB + (size_t)nr * 2048 + s * 256;
      bf16* dst = WS + c * 2056 + s * 256;
#pragma unroll
      for (int w = 0; w < 32; ++w)
        *(bf16x8*)(dst + w * 8) = *(const bf16x8*)(src + w * 8);
    }
  }
  float bsr[4][2];
  const float* bias = half ? P.bB : P.bA;
#pragma unroll
  for (int g = 0; g < 4; ++g) {
    bsr[g][0] = bias[g * 1024 + j0 + cj];
    bsr[g][1] = bias[g * 1024 + j0 + cj + 1];
  }
  float creg[2];
  const float* c0 = half ? P.cB0 : P.cA0;
  if (c0) {
    creg[0] = c0[cb * 1024 + j0 + cj];
    creg[1] = c0[cb * 1024 + j0 + cj + 1];
  } else {
    creg[0] = creg[1] = 0.f;
  }
  __syncthreads();

  for (int t = 0; t < 128; ++t) {
    // ---- issue G loads before waiting (independent of h) ----
    bf16x2 graw[4];
    if (half == 0) {
      const bf16* Gt = P.G + (size_t)t * 262144 + (size_t)cb * 4096;
#pragma unroll
      for (int g = 0; g < 4; ++g)
        graw[g] = *(const bf16x2*)(Gt + g * 1024 + j0 + cj);
    }

    // ---- wait for producers (layer-scoped, distributed) ----
    if (half == 0) {
      if (t > 0 && tid < 128) waitflag(aF + rep + tid * 8, (unsigned)t);
    } else {
      if (tid < 128) waitflag(aF + rep + tid * 8, (unsigned)(t + 1));
      else if (t > 0) waitflag(bF + rep + (tid - 128) * 8, (unsigned)t);
    }
    __syncthreads();

    f32x4 acc[8];   // [bt*2 + c]
#pragma unroll
    for (int i = 0; i < 8; ++i) acc[i] = 0;
    float gx[4][2] = {{0, 0}, {0, 0}, {0, 0}, {0, 0}};
    if (half == 0) {
#pragma unroll
      for (int g = 0; g < 4; ++g) {
        gx[g][0] = (float)graw[g].x;
        gx[g][1] = (float)graw[g].y;
      }
    }

    const bf16* srcH;
    int colbase;
    if (half == 0) {
      srcH = (t == 0) ? P.hA0 : (P.RA + (size_t)(t - 1) * 65536);
      colbase = q * 256;
    } else {
      // q 0,1 -> RA[t] halves; q 2,3 -> own h (h0 at t=0, else RB[t-1])
      srcH = (q < 2) ? (P.RA + (size_t)t * 65536)
                     : ((t == 0) ? P.hB0 : (P.RB + (size_t)(t - 1) * 65536));
      colbase = (q & 1) * 512;
    }

    if (srcH) {
      const int kb = colbase >> 3;              // k8 base for this wave
      const int NB = half ? 4 : 2;              // blocks of 4 kk
      bf16x8 ab[2][16];
      // jb-layout load: element = k8*512 + row*8
#pragma unroll
      for (int bt = 0; bt < 4; ++bt)
#pragma unroll
        for (int kk = 0; kk < 4; ++kk)
          ab[0][bt * 4 + kk] = *(const bf16x8*)(
              srcH + (size_t)(kb + kk * 4 + kh) * 512 + (bt * 16 + fr) * 8);
#pragma unroll
      for (int blk = 0; blk < 4; ++blk) {
        if (blk >= NB) break;
        if (blk + 1 < NB) {
#pragma unroll
          for (int bt = 0; bt < 4; ++bt)
#pragma unroll
            for (int kk = 0; kk < 4; ++kk)
              ab[(blk + 1) & 1][bt * 4 + kk] = *(const bf16x8*)(
                  srcH + (size_t)(kb + (blk + 1) * 16 + kk * 4 + kh) * 512 +
                  (bt * 16 + fr) * 8);
        }
#pragma unroll
        for (int kk = 0; kk < 4; ++kk) {
          bf16x8 w0 = *(const bf16x8*)(wsc0 + blk * 128 + kk * 32);
          bf16x8 w1 = *(const bf16x8*)(wsc1 + blk * 128 + kk * 32);
#pragma unroll
          for (int bt = 0; bt < 4; ++bt) {
            acc[bt * 2 + 0] = MFMA(ab[blk & 1][bt * 4 + kk], w0, acc[bt * 2 + 0], 0, 0, 0);
            acc[bt * 2 + 1] = MFMA(ab[blk & 1][bt * 4 + kk], w1, acc[bt * 2 + 1], 0, 0, 0);
          }
        }
      }
    }

    // ---- two-round k-quarter reduce in LDS ----
    if (q < 2) {
#pragma unroll
      for (int bt = 0; bt < 4; ++bt)
#pragma unroll
        for (int c = 0; c < 2; ++c)
#pragma unroll
          for (int r = 0; r < 4; ++r)
            GT(q, bt * 16 + rq + r, c * 16 + fr) = acc[bt * 2 + c][r];
    }
    __syncthreads();
    if (q >= 2) {
#pragma unroll
      for (int bt = 0; bt < 4; ++bt)
#pragma unroll
        for (int c = 0; c < 2; ++c)
#pragma unroll
          for (int r = 0; r < 4; ++r)
            GT(q - 2, bt * 16 + rq + r, c * 16 + fr) += acc[bt * 2 + c][r];
    }
    __syncthreads();

    float hn[2];
#pragma unroll
    for (int r = 0; r < 2; ++r) {
      int jj = cj + r;
      float gi = GT(0, cb, jj)      + GT(1, cb, jj)      + gx[0][r] + bsr[0][r];
      float gf = GT(0, cb, 8 + jj)  + GT(1, cb, 8 + jj)  + gx[1][r] + bsr[1][r];
      float gg = GT(0, cb, 16 + jj) + GT(1, cb, 16 + jj) + gx[2][r] + bsr[2][r];
      float go = GT(0, cb, 24 + jj) + GT(1, cb, 24 + jj) + gx[3][r] + bsr[3][r];
      float cn = sigf(gf) * creg[r] + sigf(gi) * tanhf(gg);
      creg[r] = cn;
      hn[r] = sigf(go) * tanhf(cn);
    }
    // ---- jb-layout h store: block writes 1KB contiguous (8 full lines) ----
    bf16* R = half ? P.RB : P.RA;
    union { bf16 h[2]; unsigned u; } pk;
    pk.h[0] = (bf16)hn[0];
    pk.h[1] = (bf16)hn[1];
    __hip_atomic_store((unsigned*)(R + (size_t)t * 65536 + jb * 512 + cb * 8 + cj),
                       pk.u, __ATOMIC_RELAXED, __HIP_MEMORY_SCOPE_AGENT);
    bf16* Hfin = half ? P.HfB : P.HfA;
    if (Hfin && t == 127) {
      union { bf16 h[2]; unsigned u; } e2;
      e2.h[0] = (bf16)tanhf(hn[0]);
      e2.h[1] = (bf16)tanhf(hn[1]);
      __hip_atomic_store((unsigned*)(Hfin + jb * 512 + cb * 8 + cj), e2.u,
                         __ATOMIC_RELAXED, __HIP_MEMORY_SCOPE_AGENT);
    }

    // ---- publish: drain h stores (syncthreads waits vmcnt), then set flag ----
    __syncthreads();
    if (tid < 8) {
      unsigned* F = (half ? bF : aF) + (tid << 10) + jb * 8;
      __hip_atomic_store(F, (unsigned)(t + 1), __ATOMIC_RELAXED,
                         __HIP_MEMORY_SCOPE_AGENT);
    }
  }
#undef GT
}

// ---------------- host orchestration ----------------
extern "C" void kernel_launch(void* const* d_in, const int* in_sizes, int n_in,
                              void* d_out, int out_size, void* d_ws, size_t ws_size,
                              hipStream_t stream) {
  (void)in_sizes; (void)n_in; (void)out_size; (void)ws_size;
  const float* x      = (const float*)d_in[0];
  const float* dec_c0 = (const float*)d_in[1];
  const float* eWih0 = (const float*)d_in[2];
  const float* eWhh0 = (const float*)d_in[3];
  const float* eb0   = (const float*)d_in[4];
  const float* eWih1 = (const float*)d_in[5];
  const float* eWhh1 = (const float*)d_in[6];
  const float* eb1   = (const float*)d_in[7];
  const float* dWih0 = (const float*)d_in[8];
  const float* dWhh0 = (const float*)d_in[9];
  const float* db0   = (const float*)d_in[10];
  const float* dWih1 = (const float*)d_in[11];
  const float* dWhh1 = (const float*)d_in[12];
  const float* db1   = (const float*)d_in[13];
  const float* fcW   = (const float*)d_in[14];
  const float* fcb   = (const float*)d_in[15];
  float* out = (float*)d_out;

  const int H = 1024, I = 512, T = 128, B = 64;
  const int BH = B * H;
  const size_t TBI = (size_t)T * B * I;
  const size_t TBH = (size_t)T * B * H;
  const int SMEM = 148480;  // 32*2056*2 (weights) + 2*64*33*4 (gt)

  char* p = (char*)d_ws;
  auto alloc = [&](size_t bytes) -> char* {
    char* r = p; p += (bytes + 255) & ~(size_t)255; return r;
  };
  bf16* Wih_e0 = (bf16*)alloc((size_t)4 * H * I * 2);
  bf16* Whh_e0 = (bf16*)alloc((size_t)4 * H * H * 2);
  bf16* Wcat_e1 = (bf16*)alloc((size_t)4 * H * 2 * H * 2);
  bf16* Wih_d0 = (bf16*)alloc((size_t)4 * H * I * 2);
  bf16* Whh_d0 = (bf16*)alloc((size_t)4 * H * H * 2);
  bf16* Wcat_d1 = (bf16*)alloc((size_t)4 * H * 2 * H * 2);
  bf16* Wfc = (bf16*)alloc((size_t)I * H * 2);
  bf16* xe = (bf16*)alloc(TBI * 2);
  bf16* xd = (bf16*)alloc(TBI * 2);
  bf16* henc0 = (bf16*)alloc((size_t)BH * 2);
  bf16* henc1 = (bf16*)alloc((size_t)BH * 2);
  unsigned* bars = (unsigned*)alloc(131072);
  bf16* G  = (bf16*)alloc((size_t)T * B * 4 * H * 2);   // 64 MB, reused e/d
  bf16* RA = (bf16*)alloc(TBH * 2);                     // reused e/d (jb layout)
  bf16* RB = (bf16*)alloc(TBH * 2);                     // reused e/d (jb layout)

  hipFuncSetAttribute((const void*)phase_k,
                      hipFuncAttributeMaxDynamicSharedMemorySize, SMEM);

  prep_all_k<<<133120, 256, 0, stream>>>(x, eWih0, eWhh0, eWih1, eWhh1,
                                         dWih0, dWhh0, dWih1, dWhh1, fcW,
                                         Wih_e0, Whh_e0, Wcat_e1,
                                         Wih_d0, Whh_d0, Wcat_d1,
                                         Wfc, xe, xd, bars);

  auto coop = [&](PK& pk) {
    void* args[] = { (void*)&pk };
    hipLaunchCooperativeKernel((void*)phase_k, dim3(256), dim3(256), args,
                               SMEM, stream);
  };

  // ---- encoder ----
  gemm_bt_k<<<dim3(32, 64), 256, 0, stream>>>(xe, Wih_e0, G, nullptr, nullptr,
                                              8192, 4096, 512, 0);
  PK Pe = { G, Whh_e0, eb0, nullptr, nullptr, RA,
            Wcat_e1, eb1, nullptr, nullptr, RB, henc0, henc1, bars };
  coop(Pe);

  // ---- decoder ----
  gemm_bt_k<<<dim3(32, 64), 256, 0, stream>>>(xd, Wih_d0, G, nullptr, nullptr,
                                              8192, 4096, 512, 0);
  PK Pd = { G, Whh_d0, db0, henc0, dec_c0, RA,
            Wcat_d1, db1, henc1, dec_c0 + BH, RB, nullptr, nullptr,
            bars + 16384 };
  coop(Pd);

  // ---- FC: sigmoid(RB @ fcW^T + fcb), A in jb layout (mode 2) ----
  gemm_bt_k<<<dim3(4, 64), 256, 0, stream>>>(RB, Wfc, nullptr, out, fcb,
                                             8192, 512, 1024, 2);
}